// Round 2
// baseline (553.040 us; speedup 1.0000x reference)
//
#include <hip/hip_runtime.h>

#define HIDDEN 4096
#define INTER  11008
#define MTOK   128          // B*S
#define NMERG  (2*INTER)    // 22016
#define KS1    4            // stage-1 K-split (bf16 partials, 22.5 MB)
#define KS2    16           // stage-2 K-split (fp32 partials, 33.5 MB)

typedef short          short8  __attribute__((ext_vector_type(8)));
typedef unsigned short ushort8 __attribute__((ext_vector_type(8)));
typedef float          f32x16  __attribute__((ext_vector_type(16)));
#define AS1 __attribute__((address_space(1)))
#define AS3 __attribute__((address_space(3)))

static __device__ __forceinline__ unsigned short f2bf_rne(float f) {
    unsigned u = __builtin_bit_cast(unsigned, f);
    u += 0x7FFFu + ((u >> 16) & 1u);
    return (unsigned short)(u >> 16);
}
static __device__ __forceinline__ float bf2f(unsigned short b) {
    unsigned u = (unsigned)b << 16;
    return __builtin_bit_cast(float, u);
}
// pack two fp32 -> bf16x2 by truncation (exact for integer-valued weights)
static __device__ __forceinline__ int pk2(float lo, float hi) {
    return (int)__builtin_amdgcn_perm(__builtin_bit_cast(unsigned, hi),
                                      __builtin_bit_cast(unsigned, lo),
                                      0x07060302u);
}

// ---- x fp32 -> bf16 in MFMA A-fragment order ----
// A2[((kstep*4+ms)*64+lane)*8 + j] = bf16(x[m][k]), m=ms*32+(lane&31), k=kstep*16+(lane>>5)*8+j
__global__ void cvt_x_k(const float* __restrict__ x, unsigned short* __restrict__ A2) {
    int f = blockIdx.x * 256 + threadIdx.x;
    int lane = f & 63, w = f >> 6;
    int kstep = w >> 2, ms = w & 3;
    int m = ms * 32 + (lane & 31);
    int k = kstep * 16 + (lane >> 5) * 8;
    const float* src = x + (size_t)m * HIDDEN + k;
    float4 v0 = *(const float4*)(src);
    float4 v1 = *(const float4*)(src + 4);
    ushort8 o;
    o[0] = f2bf_rne(v0.x); o[1] = f2bf_rne(v0.y); o[2] = f2bf_rne(v0.z); o[3] = f2bf_rne(v0.w);
    o[4] = f2bf_rne(v1.x); o[5] = f2bf_rne(v1.y); o[6] = f2bf_rne(v1.z); o[7] = f2bf_rne(v1.w);
    *(ushort8*)(A2 + (size_t)f * 8) = o;
}

// ---- LDS-staged dequant GEMM partial, barrier-free per-wave pipeline ----
// part[ks][m][n] = sum_{k chunk} A[m][k]*B[n][k].  BN=128 rows/block, BK=64 fp32.
// Each wave reads ONLY the LDS region it stages itself (rows ws*32..ws*32+31),
// so no __syncthreads is needed. Double-buffered 8KB/wave regions; tile t+2
// staged while computing tile t; counted s_waitcnt vmcnt(8) keeps 8-16 loads
// in flight per wave at all times (T3/T4: never drain vmcnt to 0 in the loop).
// vmcnt retires in order, so leaving the newest 8 events (= the t+2 stage)
// proves tile t's stage AND all interleaved A-fragment L2 loads have landed.
template<bool OBF16>
__global__ __launch_bounds__(256) void gemm_k(
    const unsigned short* __restrict__ A2,
    const float* __restrict__ B0, const float* __restrict__ B1, int nhalf,
    void* __restrict__ part, int K, int N, int totTiles, int ksplit)
{
    __shared__ __align__(16) float lds[16384];  // 2 buffers x 128 rows x 16 atoms(16B)
    const int lane = threadIdx.x & 63;
    const int ws   = threadIdx.x >> 6;
    const int n0   = blockIdx.x * 128;
    const int ks   = blockIdx.y;
    const int tbeg = (ks * totTiles) / ksplit;
    const int tend = ((ks + 1) * totTiles) / ksplit;
    const int nt   = tend - tbeg;

    // per-lane global staging bases (8 issues/wave, 1KB each), XOR-16 atom swizzle
    const char* gbase[8];
#pragma unroll
    for (int i = 0; i < 8; ++i) {
        int s = ws * 512 + i * 64 + lane;          // LDS atom slot
        int n = s >> 4;                            // tile-local row
        int a = (s & 15) ^ (n & 15);               // swizzled source atom
        const float* rowp = (n0 + n < nhalf) ? (B0 + (size_t)(n0 + n) * K)
                                             : (B1 + (size_t)(n0 + n - nhalf) * K);
        gbase[i] = (const char*)rowp + a * 16;
    }

    f32x16 acc[4];
#pragma unroll
    for (int t = 0; t < 4; ++t)
#pragma unroll
        for (int r = 0; r < 16; ++r) acc[t][r] = 0.f;

    const int nl = ws * 32 + (lane & 31);          // tile-local weight row this lane consumes

    // stage tile t (global index) into buffer buf: 8 x global_load_lds of 16B/lane
    auto stage = [&](int t, int buf) {
        const size_t koff = (size_t)t * 64 * 4;    // byte offset along row
#pragma unroll
        for (int i = 0; i < 8; ++i) {
            __builtin_amdgcn_global_load_lds(
                (const AS1 unsigned*)(gbase[i] + koff),
                (AS3 unsigned*)((char*)lds + buf * 32768 + ws * 8192 + i * 1024), 16, 0, 0);
        }
    };

    // prologue: fill both buffers
    stage(tbeg, 0);
    if (nt > 1) stage(tbeg + 1, 1);

    for (int i = 0; i < nt; ++i) {
        // wait for tile i's 8 loads; tile i+1's 8 stay in flight
        if (i + 1 < nt) { asm volatile("s_waitcnt vmcnt(8)" ::: "memory"); }
        else            { asm volatile("s_waitcnt vmcnt(0)" ::: "memory"); }
        __builtin_amdgcn_sched_barrier(0);

        const int t = tbeg + i;
        const char* lbase = (const char*)lds + (size_t)(i & 1) * 32768;
#pragma unroll
        for (int step = 0; step < 4; ++step) {
            int a0 = step * 4 + ((lane >> 5) << 1);
            int p0 = nl * 16 + (a0 ^ (nl & 15));
            int p1 = nl * 16 + ((a0 + 1) ^ (nl & 15));
            float4 v0 = *(const float4*)(lbase + p0 * 16);
            float4 v1 = *(const float4*)(lbase + p1 * 16);
            int4 bi;
            bi.x = pk2(v0.x, v0.y); bi.y = pk2(v0.z, v0.w);
            bi.z = pk2(v1.x, v1.y); bi.w = pk2(v1.z, v1.w);
            short8 bf = __builtin_bit_cast(short8, bi);
            int kg = t * 4 + step;                 // global 16-k step index
#pragma unroll
            for (int ms = 0; ms < 4; ++ms) {
                short8 af = *(const short8*)(A2 + ((size_t)(kg * 4 + ms) * 64 + lane) * 8);
                acc[ms] = __builtin_amdgcn_mfma_f32_32x32x16_bf16(af, bf, acc[ms], 0, 0, 0);
            }
        }

        // refill the buffer just consumed with tile t+2 (WAR: all ds_reads done first)
        if (i + 2 < nt) {
            asm volatile("s_waitcnt lgkmcnt(0)" ::: "memory");
            __builtin_amdgcn_sched_barrier(0);
            stage(t + 2, i & 1);
        }
    }

    // C/D layout: col=lane&31, row=(r&3)+8*(r>>2)+4*(lane>>5)
    const int n = n0 + ws * 32 + (lane & 31);
#pragma unroll
    for (int ms = 0; ms < 4; ++ms)
#pragma unroll
        for (int r = 0; r < 16; ++r) {
            int m = ms * 32 + (r & 3) + 8 * (r >> 2) + 4 * (lane >> 5);
            size_t idx = ((size_t)ks * MTOK + m) * (size_t)N + n;
            if (OBF16) ((unsigned short*)part)[idx] = f2bf_rne(acc[ms][r]);
            else       ((float*)part)[idx] = acc[ms][r];
        }
}

// ---- combine KS1 bf16 partials, scale, SwiGLU -> h in fragment order ----
__global__ void swiglu_k(const unsigned short* __restrict__ p1,  // [KS1][MTOK][NMERG] bf16
                         const float* __restrict__ s1, const float* __restrict__ s3,
                         unsigned short* __restrict__ h2)        // fragment-ordered, K=INTER
{
    int f = blockIdx.x * 256 + threadIdx.x;
    int lane = f & 63, w = f >> 6;
    int kstep = w >> 2, ms = w & 3;
    int m = ms * 32 + (lane & 31);
    int j = kstep * 16 + (lane >> 5) * 8;
    float up[8], gt[8];
#pragma unroll
    for (int e = 0; e < 8; ++e) { up[e] = 0.f; gt[e] = 0.f; }
#pragma unroll
    for (int ks = 0; ks < KS1; ++ks) {
        const unsigned short* pu = p1 + ((size_t)ks * MTOK + m) * NMERG + j;
        ushort8 u = *(const ushort8*)(pu);
        ushort8 g = *(const ushort8*)(pu + INTER);
#pragma unroll
        for (int e = 0; e < 8; ++e) { up[e] += bf2f(u[e]); gt[e] += bf2f(g[e]); }
    }
    float4 c1a = *(const float4*)(s1 + j), c1b = *(const float4*)(s1 + j + 4);
    float4 c3a = *(const float4*)(s3 + j), c3b = *(const float4*)(s3 + j + 4);
    float c1[8] = {c1a.x, c1a.y, c1a.z, c1a.w, c1b.x, c1b.y, c1b.z, c1b.w};
    float c3[8] = {c3a.x, c3a.y, c3a.z, c3a.w, c3b.x, c3b.y, c3b.z, c3b.w};
    ushort8 o;
#pragma unroll
    for (int e = 0; e < 8; ++e) {
        float u = up[e] * c1[e], g = gt[e] * c3[e];
        o[e] = f2bf_rne(g * u / (1.f + __expf(-u)));
    }
    *(ushort8*)(h2 + (size_t)f * 8) = o;
}

// ---- reduce KS2 fp32 partials, scale by w2_s ----
__global__ void reduce_k(const float* __restrict__ p, const float* __restrict__ s2,
                         float* __restrict__ out)
{
    int i = (blockIdx.x * 256 + threadIdx.x) * 4;
    float4 acc = *(const float4*)(p + i);
#pragma unroll
    for (int s = 1; s < KS2; ++s) {
        float4 v = *(const float4*)(p + (size_t)s * MTOK * HIDDEN + i);
        acc.x += v.x; acc.y += v.y; acc.z += v.z; acc.w += v.w;
    }
    int ncol = i & (HIDDEN - 1);
    float4 sc = *(const float4*)(s2 + ncol);
    acc.x *= sc.x; acc.y *= sc.y; acc.z *= sc.z; acc.w *= sc.w;
    *(float4*)(out + i) = acc;
}

extern "C" void kernel_launch(void* const* d_in, const int* in_sizes, int n_in,
                              void* d_out, int out_size, void* d_ws, size_t ws_size,
                              hipStream_t stream) {
    const float* x   = (const float*)d_in[0];
    const float* w1q = (const float*)d_in[1];
    const float* w1s = (const float*)d_in[2];
    const float* w3q = (const float*)d_in[3];
    const float* w3s = (const float*)d_in[4];
    const float* w2q = (const float*)d_in[5];
    const float* w2s = (const float*)d_in[6];
    float* out = (float*)d_out;

    char* ws = (char*)d_ws;
    unsigned short* xb2 = (unsigned short*)ws;                 // 1 MB   fragment-ordered x
    unsigned short* h2  = (unsigned short*)(ws + (1u << 20));  // 2.75 MB fragment-ordered h
    void* part          = (void*)(ws + (4u << 20));            // max 33.5 MB partials

    // 1) x -> bf16 fragments
    cvt_x_k<<<MTOK * HIDDEN / 8 / 256, 256, 0, stream>>>(x, xb2);
    // 2) up/gate: merged [w1;w3], N=22016, K=4096, 64 tiles, K-split 4, bf16 partials
    gemm_k<true><<<dim3(NMERG / 128, KS1), 256, 0, stream>>>(
        xb2, w1q, w3q, INTER, part, HIDDEN, NMERG, HIDDEN / 64, KS1);
    // 3) SwiGLU -> h fragments
    swiglu_k<<<MTOK * INTER / 8 / 256, 256, 0, stream>>>(
        (const unsigned short*)part, w1s, w3s, h2);
    // 4) out: w2, N=4096, K=11008, 172 tiles, K-split 16, fp32 partials
    gemm_k<false><<<dim3(HIDDEN / 128, KS2), 256, 0, stream>>>(
        h2, w2q, w2q, 1 << 30, part, INTER, HIDDEN, INTER / 64, KS2);
    // 5) reduce + scale
    reduce_k<<<MTOK * HIDDEN / 4 / 256, 256, 0, stream>>>(
        (const float*)part, w2s, out);
}

// Round 3
// 528.920 us; speedup vs baseline: 1.0456x; 1.0456x over previous
//
#include <hip/hip_runtime.h>

#define HIDDEN 4096
#define INTER  11008
#define MTOK   128          // B*S
#define NMERG  (2*INTER)    // 22016
#define KS1    4            // stage-1 K-split (bf16 partials, 22.5 MB)
#define KS2    16           // stage-2 K-split (fp32 partials, 33.5 MB)

typedef short          short8  __attribute__((ext_vector_type(8)));
typedef unsigned short ushort8 __attribute__((ext_vector_type(8)));
typedef float          f32x16  __attribute__((ext_vector_type(16)));
#define AS1 __attribute__((address_space(1)))
#define AS3 __attribute__((address_space(3)))

static __device__ __forceinline__ unsigned short f2bf_rne(float f) {
    unsigned u = __builtin_bit_cast(unsigned, f);
    u += 0x7FFFu + ((u >> 16) & 1u);
    return (unsigned short)(u >> 16);
}
static __device__ __forceinline__ float bf2f(unsigned short b) {
    unsigned u = (unsigned)b << 16;
    return __builtin_bit_cast(float, u);
}
// pack two fp32 -> bf16x2 by truncation (exact for integer-valued weights)
static __device__ __forceinline__ int pk2(float lo, float hi) {
    return (int)__builtin_amdgcn_perm(__builtin_bit_cast(unsigned, hi),
                                      __builtin_bit_cast(unsigned, lo),
                                      0x07060302u);
}

// ---- x fp32 -> bf16 in MFMA A-fragment order ----
// A2[((kstep*4+ms)*64+lane)*8 + j] = bf16(x[m][k]), m=ms*32+(lane&31), k=kstep*16+(lane>>5)*8+j
__global__ void cvt_x_k(const float* __restrict__ x, unsigned short* __restrict__ A2) {
    int f = blockIdx.x * 256 + threadIdx.x;
    int lane = f & 63, w = f >> 6;
    int kstep = w >> 2, ms = w & 3;
    int m = ms * 32 + (lane & 31);
    int k = kstep * 16 + (lane >> 5) * 8;
    const float* src = x + (size_t)m * HIDDEN + k;
    float4 v0 = *(const float4*)(src);
    float4 v1 = *(const float4*)(src + 4);
    ushort8 o;
    o[0] = f2bf_rne(v0.x); o[1] = f2bf_rne(v0.y); o[2] = f2bf_rne(v0.z); o[3] = f2bf_rne(v0.w);
    o[4] = f2bf_rne(v1.x); o[5] = f2bf_rne(v1.y); o[6] = f2bf_rne(v1.z); o[7] = f2bf_rne(v1.w);
    *(ushort8*)(A2 + (size_t)f * 8) = o;
}

// ---- LDS-staged dequant GEMM partial, barrier-free per-wave pipeline ----
// part[ks][m][n] = sum_{k chunk} A[m][k]*B[n][k].  BN=128 rows/block, BK=64 fp32.
// Each wave reads ONLY the LDS it stages itself -> no __syncthreads.
// KEY FIX vs r1: compute phase now contains ZERO VMEM ops. A-fragments are
// register-double-buffered (A0/A1, loaded in the refill segment next to the
// B stage), so the compiler's waitcnt for A-use cannot drain the B prefetch
// (in-order vmcnt retirement made any in-compute A-load wait an effective
// vmcnt(0) in r1 -> pipeline depth 0 -> unchanged BW). Steady state keeps
// stage(i+1)+A(i+1) = 24 loads (24KB/wave) in flight across the whole
// compute phase; wait is vmcnt(24), never 0, until the epilogue.
template<bool OBF16>
__global__ __launch_bounds__(256) void gemm_k(
    const unsigned short* __restrict__ A2,
    const float* __restrict__ B0, const float* __restrict__ B1, int nhalf,
    void* __restrict__ part, int K, int N, int totTiles, int ksplit)
{
    __shared__ __align__(16) float lds[16384];  // 2 buffers x 128 rows x 16 atoms(16B)
    const int lane = threadIdx.x & 63;
    const int ws   = threadIdx.x >> 6;
    const int n0   = blockIdx.x * 128;
    const int ks   = blockIdx.y;
    const int tbeg = (ks * totTiles) / ksplit;
    const int tend = ((ks + 1) * totTiles) / ksplit;
    const int nt   = tend - tbeg;

    // per-lane global staging bases (8 issues/wave, 1KB each), XOR-16 atom swizzle
    const char* gbase[8];
#pragma unroll
    for (int i = 0; i < 8; ++i) {
        int s = ws * 512 + i * 64 + lane;          // LDS atom slot
        int n = s >> 4;                            // tile-local row
        int a = (s & 15) ^ (n & 15);               // swizzled source atom
        const float* rowp = (n0 + n < nhalf) ? (B0 + (size_t)(n0 + n) * K)
                                             : (B1 + (size_t)(n0 + n - nhalf) * K);
        gbase[i] = (const char*)rowp + a * 16;
    }

    f32x16 acc[4];
#pragma unroll
    for (int t = 0; t < 4; ++t)
#pragma unroll
        for (int r = 0; r < 16; ++r) acc[t][r] = 0.f;

    const int nl = ws * 32 + (lane & 31);          // tile-local weight row this lane consumes

    // stage tile t into LDS buffer buf: 8 x global_load_lds of 16B/lane
    auto stage = [&](int t, int buf) {
        const size_t koff = (size_t)t * 64 * 4;    // byte offset along row
#pragma unroll
        for (int i = 0; i < 8; ++i) {
            __builtin_amdgcn_global_load_lds(
                (const AS1 unsigned*)(gbase[i] + koff),
                (AS3 unsigned*)((char*)lds + buf * 32768 + ws * 8192 + i * 1024), 16, 0, 0);
        }
    };
    // load tile t's A-fragments into a register buffer (16 x dwordx4)
    auto loadA = [&](int t, short8 (&Ar)[16]) {
#pragma unroll
        for (int r = 0; r < 16; ++r) {
            int kg = t * 4 + (r >> 2), ms = r & 3;
            Ar[r] = *(const short8*)(A2 + ((size_t)(kg * 4 + ms) * 64 + lane) * 8);
        }
    };

    short8 A0[16], A1[16];

    // one pipeline step: consume tile i (LDS buf i&1, regs Ar), refill for i+2
    auto iter = [&](int i, short8 (&Ar)[16]) {
        // stage(i)+A(i) retired; stage(i+1)+A(i+1) (24 newest) stay in flight
        if (i + 1 < nt) { asm volatile("s_waitcnt vmcnt(24)" ::: "memory"); }
        else            { asm volatile("s_waitcnt vmcnt(0)" ::: "memory"); }
        __builtin_amdgcn_sched_barrier(0);

        const char* lbase = (const char*)lds + (size_t)(i & 1) * 32768;
#pragma unroll
        for (int step = 0; step < 4; ++step) {
            int a0 = step * 4 + ((lane >> 5) << 1);
            int p0 = nl * 16 + (a0 ^ (nl & 15));
            int p1 = nl * 16 + ((a0 + 1) ^ (nl & 15));
            float4 v0 = *(const float4*)(lbase + p0 * 16);
            float4 v1 = *(const float4*)(lbase + p1 * 16);
            int4 bi;
            bi.x = pk2(v0.x, v0.y); bi.y = pk2(v0.z, v0.w);
            bi.z = pk2(v1.x, v1.y); bi.w = pk2(v1.z, v1.w);
            short8 bf = __builtin_bit_cast(short8, bi);
#pragma unroll
            for (int ms = 0; ms < 4; ++ms)
                acc[ms] = __builtin_amdgcn_mfma_f32_32x32x16_bf16(Ar[step * 4 + ms], bf, acc[ms], 0, 0, 0);
        }

        // refill the LDS buffer + A-regs just consumed with tile i+2
        if (i + 2 < nt) {
            asm volatile("s_waitcnt lgkmcnt(0)" ::: "memory");   // WAR: ds_reads done
            __builtin_amdgcn_sched_barrier(0);
            stage(tbeg + i + 2, i & 1);
            loadA(tbeg + i + 2, Ar);
        }
    };

    // prologue: fill both LDS buffers and both A-reg buffers
    stage(tbeg, 0);
    loadA(tbeg, A0);
    if (nt > 1) { stage(tbeg + 1, 1); loadA(tbeg + 1, A1); }

    for (int i = 0; i < nt; i += 2) {
        iter(i, A0);
        if (i + 1 < nt) iter(i + 1, A1);
    }

    // C/D layout: col=lane&31, row=(r&3)+8*(r>>2)+4*(lane>>5)
    const int n = n0 + ws * 32 + (lane & 31);
#pragma unroll
    for (int ms = 0; ms < 4; ++ms)
#pragma unroll
        for (int r = 0; r < 16; ++r) {
            int m = ms * 32 + (r & 3) + 8 * (r >> 2) + 4 * (lane >> 5);
            size_t idx = ((size_t)ks * MTOK + m) * (size_t)N + n;
            if (OBF16) ((unsigned short*)part)[idx] = f2bf_rne(acc[ms][r]);
            else       ((float*)part)[idx] = acc[ms][r];
        }
}

// ---- combine KS1 bf16 partials, scale, SwiGLU -> h in fragment order ----
__global__ void swiglu_k(const unsigned short* __restrict__ p1,  // [KS1][MTOK][NMERG] bf16
                         const float* __restrict__ s1, const float* __restrict__ s3,
                         unsigned short* __restrict__ h2)        // fragment-ordered, K=INTER
{
    int f = blockIdx.x * 256 + threadIdx.x;
    int lane = f & 63, w = f >> 6;
    int kstep = w >> 2, ms = w & 3;
    int m = ms * 32 + (lane & 31);
    int j = kstep * 16 + (lane >> 5) * 8;
    float up[8], gt[8];
#pragma unroll
    for (int e = 0; e < 8; ++e) { up[e] = 0.f; gt[e] = 0.f; }
#pragma unroll
    for (int ks = 0; ks < KS1; ++ks) {
        const unsigned short* pu = p1 + ((size_t)ks * MTOK + m) * NMERG + j;
        ushort8 u = *(const ushort8*)(pu);
        ushort8 g = *(const ushort8*)(pu + INTER);
#pragma unroll
        for (int e = 0; e < 8; ++e) { up[e] += bf2f(u[e]); gt[e] += bf2f(g[e]); }
    }
    float4 c1a = *(const float4*)(s1 + j), c1b = *(const float4*)(s1 + j + 4);
    float4 c3a = *(const float4*)(s3 + j), c3b = *(const float4*)(s3 + j + 4);
    float c1[8] = {c1a.x, c1a.y, c1a.z, c1a.w, c1b.x, c1b.y, c1b.z, c1b.w};
    float c3[8] = {c3a.x, c3a.y, c3a.z, c3a.w, c3b.x, c3b.y, c3b.z, c3b.w};
    ushort8 o;
#pragma unroll
    for (int e = 0; e < 8; ++e) {
        float u = up[e] * c1[e], g = gt[e] * c3[e];
        o[e] = f2bf_rne(g * u / (1.f + __expf(-u)));
    }
    *(ushort8*)(h2 + (size_t)f * 8) = o;
}

// ---- reduce KS2 fp32 partials, scale by w2_s ----
__global__ void reduce_k(const float* __restrict__ p, const float* __restrict__ s2,
                         float* __restrict__ out)
{
    int i = (blockIdx.x * 256 + threadIdx.x) * 4;
    float4 acc = *(const float4*)(p + i);
#pragma unroll
    for (int s = 1; s < KS2; ++s) {
        float4 v = *(const float4*)(p + (size_t)s * MTOK * HIDDEN + i);
        acc.x += v.x; acc.y += v.y; acc.z += v.z; acc.w += v.w;
    }
    int ncol = i & (HIDDEN - 1);
    float4 sc = *(const float4*)(s2 + ncol);
    acc.x *= sc.x; acc.y *= sc.y; acc.z *= sc.z; acc.w *= sc.w;
    *(float4*)(out + i) = acc;
}

extern "C" void kernel_launch(void* const* d_in, const int* in_sizes, int n_in,
                              void* d_out, int out_size, void* d_ws, size_t ws_size,
                              hipStream_t stream) {
    const float* x   = (const float*)d_in[0];
    const float* w1q = (const float*)d_in[1];
    const float* w1s = (const float*)d_in[2];
    const float* w3q = (const float*)d_in[3];
    const float* w3s = (const float*)d_in[4];
    const float* w2q = (const float*)d_in[5];
    const float* w2s = (const float*)d_in[6];
    float* out = (float*)d_out;

    char* ws = (char*)d_ws;
    unsigned short* xb2 = (unsigned short*)ws;                 // 1 MB   fragment-ordered x
    unsigned short* h2  = (unsigned short*)(ws + (1u << 20));  // 2.75 MB fragment-ordered h
    void* part          = (void*)(ws + (4u << 20));            // max 33.5 MB partials

    // 1) x -> bf16 fragments
    cvt_x_k<<<MTOK * HIDDEN / 8 / 256, 256, 0, stream>>>(x, xb2);
    // 2) up/gate: merged [w1;w3], N=22016, K=4096, 64 tiles, K-split 4, bf16 partials
    gemm_k<true><<<dim3(NMERG / 128, KS1), 256, 0, stream>>>(
        xb2, w1q, w3q, INTER, part, HIDDEN, NMERG, HIDDEN / 64, KS1);
    // 3) SwiGLU -> h fragments
    swiglu_k<<<MTOK * INTER / 8 / 256, 256, 0, stream>>>(
        (const unsigned short*)part, w1s, w3s, h2);
    // 4) out: w2, N=4096, K=11008, 172 tiles, K-split 16, fp32 partials
    gemm_k<false><<<dim3(HIDDEN / 128, KS2), 256, 0, stream>>>(
        h2, w2q, w2q, 1 << 30, part, INTER, HIDDEN, INTER / 64, KS2);
    // 5) reduce + scale
    reduce_k<<<MTOK * HIDDEN / 4 / 256, 256, 0, stream>>>(
        (const float*)part, w2s, out);
}

// Round 4
// 513.695 us; speedup vs baseline: 1.0766x; 1.0296x over previous
//
#include <hip/hip_runtime.h>

#define HIDDEN 4096
#define INTER  11008
#define MTOK   128          // B*S
#define NMERG  (2*INTER)    // 22016
#define KS1    1            // stage-1 K-split (none: grid is 688 n-blocks already)
#define KS2    4            // stage-2 K-split (fp32 partials, 8.4 MB)
#define SK     256          // super-tile k-depth in floats = 1KB/row per stage
#define RST    1040         // LDS row stride (bytes): 1KB data + 16B pad (bank phase +4/row)
#define TILE   (32*RST)     // 33280 B per buffer

typedef short          short8  __attribute__((ext_vector_type(8)));
typedef unsigned short ushort8 __attribute__((ext_vector_type(8)));
typedef float          f32x16  __attribute__((ext_vector_type(16)));
#define AS1 __attribute__((address_space(1)))
#define AS3 __attribute__((address_space(3)))

static __device__ __forceinline__ unsigned short f2bf_rne(float f) {
    unsigned u = __builtin_bit_cast(unsigned, f);
    u += 0x7FFFu + ((u >> 16) & 1u);
    return (unsigned short)(u >> 16);
}
static __device__ __forceinline__ float bf2f(unsigned short b) {
    unsigned u = (unsigned)b << 16;
    return __builtin_bit_cast(float, u);
}
// pack two fp32 -> bf16x2 by truncation (exact for integer-valued weights)
static __device__ __forceinline__ int pk2(float lo, float hi) {
    return (int)__builtin_amdgcn_perm(__builtin_bit_cast(unsigned, hi),
                                      __builtin_bit_cast(unsigned, lo),
                                      0x07060302u);
}

// ---- x fp32 -> bf16 in MFMA A-fragment order ----
// A2[((kstep*4+ms)*64+lane)*8 + j] = bf16(x[m][k]), m=ms*32+(lane&31), k=kstep*16+(lane>>5)*8+j
__global__ void cvt_x_k(const float* __restrict__ x, unsigned short* __restrict__ A2) {
    int f = blockIdx.x * 256 + threadIdx.x;
    int lane = f & 63, w = f >> 6;
    int kstep = w >> 2, ms = w & 3;
    int m = ms * 32 + (lane & 31);
    int k = kstep * 16 + (lane >> 5) * 8;
    const float* src = x + (size_t)m * HIDDEN + k;
    float4 v0 = *(const float4*)(src);
    float4 v1 = *(const float4*)(src + 4);
    ushort8 o;
    o[0] = f2bf_rne(v0.x); o[1] = f2bf_rne(v0.y); o[2] = f2bf_rne(v0.z); o[3] = f2bf_rne(v0.w);
    o[4] = f2bf_rne(v1.x); o[5] = f2bf_rne(v1.y); o[6] = f2bf_rne(v1.z); o[7] = f2bf_rne(v1.w);
    *(ushort8*)(A2 + (size_t)f * 8) = o;
}

// ---- dequant GEMM partial, DRAM-burst-friendly tiles ----
// BN=32 rows/block, SK=256 floats (1KB/row) per super-tile. Every
// global_load_lds instruction reads 1KB CONTIGUOUS from ONE weight row
// (64 lanes x 16B) -> 4x fewer DRAM page activations than the old
// 128-rows x 256B tiles (r3 showed we're DRAM-granularity-limited, not
// latency-limited: 2x pipeline depth moved BW only +19%).
// The 4 waves split M (wave ws owns m-rows ws*32..+31) and SHARE the B-tile:
// block-cooperative staging (8 rows/wave), raw s_barrier + counted vmcnt(24)
// pipeline (never drains in-loop). A-fragments register-double-buffered so
// the compute phase has zero VMEM (r2 lesson).
template<bool OBF16>
__global__ __launch_bounds__(256) void gemm_k(
    const unsigned short* __restrict__ A2,
    const float* __restrict__ B0, const float* __restrict__ B1, int nhalf,
    void* __restrict__ part, int K, int N, int totTiles, int ksplit)
{
    __shared__ __align__(16) char lds[2 * TILE];   // 66560 B -> 2 blocks/CU
    const int lane = threadIdx.x & 63;
    const int ws   = threadIdx.x >> 6;
    const int n0   = blockIdx.x * 32;
    const int ks   = blockIdx.y;
    const int tbeg = (ks * totTiles) / ksplit;
    const int tend = ((ks + 1) * totTiles) / ksplit;
    const int nt   = tend - tbeg;

    // 8 rows this wave stages; each instruction: 1KB contiguous of one row
    const char* rowp[8];
#pragma unroll
    for (int r = 0; r < 8; ++r) {
        int n = n0 + ws * 8 + r;
        const float* p = (n < nhalf) ? B0 + (size_t)n * K
                                     : B1 + (size_t)(n - nhalf) * K;
        rowp[r] = (const char*)p + lane * 16;
    }

    f32x16 acc;
#pragma unroll
    for (int r = 0; r < 16; ++r) acc[r] = 0.f;

    auto stage = [&](int t, int buf) {
        const size_t koff = (size_t)t * (SK * 4);
#pragma unroll
        for (int r = 0; r < 8; ++r) {
            __builtin_amdgcn_global_load_lds(
                (const AS1 unsigned*)(rowp[r] + koff),
                (AS3 unsigned*)(lds + buf * TILE + (ws * 8 + r) * RST), 16, 0, 0);
        }
    };
    auto loadA = [&](int t, short8 (&Ar)[16]) {
#pragma unroll
        for (int s = 0; s < 16; ++s) {
            int kg = t * 16 + s;                   // global 16-k step
            Ar[s] = *(const short8*)(A2 + ((size_t)(kg * 4 + ws) * 64 + lane) * 8);
        }
    };

    short8 A0v[16], A1v[16];

    auto iter = [&](int i, short8 (&Ar)[16]) {
        // own stage(i)+A(i) retired; stage(i+1)+A(i+1) (24 newest) in flight
        if (i + 1 < nt) { asm volatile("s_waitcnt vmcnt(24)" ::: "memory"); }
        else            { asm volatile("s_waitcnt vmcnt(0)"  ::: "memory"); }
        __builtin_amdgcn_sched_barrier(0);
        __builtin_amdgcn_s_barrier();              // all waves' tile-i writes landed

        const char* lb = lds + (size_t)(i & 1) * TILE
                       + (lane & 31) * RST + (lane >> 5) * 32;
#pragma unroll
        for (int s = 0; s < 16; ++s) {
            float4 v0 = *(const float4*)(lb + s * 64);
            float4 v1 = *(const float4*)(lb + s * 64 + 16);
            int4 bi;
            bi.x = pk2(v0.x, v0.y); bi.y = pk2(v0.z, v0.w);
            bi.z = pk2(v1.x, v1.y); bi.w = pk2(v1.z, v1.w);
            short8 bf = __builtin_bit_cast(short8, bi);
            acc = __builtin_amdgcn_mfma_f32_32x32x16_bf16(Ar[s], bf, acc, 0, 0, 0);
        }

        asm volatile("s_waitcnt lgkmcnt(0)" ::: "memory");   // WAR: ds_reads done
        __builtin_amdgcn_sched_barrier(0);
        __builtin_amdgcn_s_barrier();              // all waves done reading buf i&1
        if (i + 2 < nt) { stage(tbeg + i + 2, i & 1); loadA(tbeg + i + 2, Ar); }
    };

    // prologue: fill both buffers
    stage(tbeg, 0); loadA(tbeg, A0v);
    if (nt > 1) { stage(tbeg + 1, 1); loadA(tbeg + 1, A1v); }

    for (int i = 0; i < nt; i += 2) {
        iter(i, A0v);
        if (i + 1 < nt) iter(i + 1, A1v);
    }

    // C/D layout: col=lane&31 -> n; row=(r&3)+8*(r>>2)+4*(lane>>5) -> m (wave owns ms=ws)
    const int n = n0 + (lane & 31);
#pragma unroll
    for (int r = 0; r < 16; ++r) {
        int m = ws * 32 + (r & 3) + 8 * (r >> 2) + 4 * (lane >> 5);
        size_t idx = ((size_t)ks * MTOK + m) * (size_t)N + n;
        if (OBF16) ((unsigned short*)part)[idx] = f2bf_rne(acc[r]);
        else       ((float*)part)[idx] = acc[r];
    }
}

// ---- combine KS1 bf16 partials, scale, SwiGLU -> h in fragment order ----
__global__ void swiglu_k(const unsigned short* __restrict__ p1,  // [KS1][MTOK][NMERG] bf16
                         const float* __restrict__ s1, const float* __restrict__ s3,
                         unsigned short* __restrict__ h2)        // fragment-ordered, K=INTER
{
    int f = blockIdx.x * 256 + threadIdx.x;
    int lane = f & 63, w = f >> 6;
    int kstep = w >> 2, ms = w & 3;
    int m = ms * 32 + (lane & 31);
    int j = kstep * 16 + (lane >> 5) * 8;
    float up[8], gt[8];
#pragma unroll
    for (int e = 0; e < 8; ++e) { up[e] = 0.f; gt[e] = 0.f; }
#pragma unroll
    for (int ks = 0; ks < KS1; ++ks) {
        const unsigned short* pu = p1 + ((size_t)ks * MTOK + m) * NMERG + j;
        ushort8 u = *(const ushort8*)(pu);
        ushort8 g = *(const ushort8*)(pu + INTER);
#pragma unroll
        for (int e = 0; e < 8; ++e) { up[e] += bf2f(u[e]); gt[e] += bf2f(g[e]); }
    }
    float4 c1a = *(const float4*)(s1 + j), c1b = *(const float4*)(s1 + j + 4);
    float4 c3a = *(const float4*)(s3 + j), c3b = *(const float4*)(s3 + j + 4);
    float c1[8] = {c1a.x, c1a.y, c1a.z, c1a.w, c1b.x, c1b.y, c1b.z, c1b.w};
    float c3[8] = {c3a.x, c3a.y, c3a.z, c3a.w, c3b.x, c3b.y, c3b.z, c3b.w};
    ushort8 o;
#pragma unroll
    for (int e = 0; e < 8; ++e) {
        float u = up[e] * c1[e], g = gt[e] * c3[e];
        o[e] = f2bf_rne(g * u / (1.f + __expf(-u)));
    }
    *(ushort8*)(h2 + (size_t)f * 8) = o;
}

// ---- reduce KS2 fp32 partials, scale by w2_s ----
__global__ void reduce_k(const float* __restrict__ p, const float* __restrict__ s2,
                         float* __restrict__ out)
{
    int i = (blockIdx.x * 256 + threadIdx.x) * 4;
    float4 acc = *(const float4*)(p + i);
#pragma unroll
    for (int s = 1; s < KS2; ++s) {
        float4 v = *(const float4*)(p + (size_t)s * MTOK * HIDDEN + i);
        acc.x += v.x; acc.y += v.y; acc.z += v.z; acc.w += v.w;
    }
    int ncol = i & (HIDDEN - 1);
    float4 sc = *(const float4*)(s2 + ncol);
    acc.x *= sc.x; acc.y *= sc.y; acc.z *= sc.z; acc.w *= sc.w;
    *(float4*)(out + i) = acc;
}

extern "C" void kernel_launch(void* const* d_in, const int* in_sizes, int n_in,
                              void* d_out, int out_size, void* d_ws, size_t ws_size,
                              hipStream_t stream) {
    const float* x   = (const float*)d_in[0];
    const float* w1q = (const float*)d_in[1];
    const float* w1s = (const float*)d_in[2];
    const float* w3q = (const float*)d_in[3];
    const float* w3s = (const float*)d_in[4];
    const float* w2q = (const float*)d_in[5];
    const float* w2s = (const float*)d_in[6];
    float* out = (float*)d_out;

    char* ws = (char*)d_ws;
    unsigned short* xb2 = (unsigned short*)ws;                 // 1 MB   fragment-ordered x
    unsigned short* h2  = (unsigned short*)(ws + (1u << 20));  // 2.75 MB fragment-ordered h
    void* part          = (void*)(ws + (4u << 20));            // 5.5 MB bf16 / 8.4 MB fp32 partials

    // 1) x -> bf16 fragments
    cvt_x_k<<<MTOK * HIDDEN / 8 / 256, 256, 0, stream>>>(x, xb2);
    // 2) up/gate: merged [w1;w3], N=22016, K=4096, 16 super-tiles, no K-split
    gemm_k<true><<<dim3(NMERG / 32, KS1), 256, 0, stream>>>(
        xb2, w1q, w3q, INTER, part, HIDDEN, NMERG, HIDDEN / SK, KS1);
    // 3) SwiGLU -> h fragments
    swiglu_k<<<MTOK * INTER / 8 / 256, 256, 0, stream>>>(
        (const unsigned short*)part, w1s, w3s, h2);
    // 4) out: w2, N=4096, K=11008, 43 super-tiles, K-split 4 (grid 512 = 2/CU exactly)
    gemm_k<false><<<dim3(HIDDEN / 32, KS2), 256, 0, stream>>>(
        h2, w2q, w2q, 1 << 30, part, INTER, HIDDEN, INTER / SK, KS2);
    // 5) reduce + scale
    reduce_k<<<MTOK * HIDDEN / 4 / 256, 256, 0, stream>>>(
        (const float*)part, w2s, out);
}